// Round 4
// baseline (752.032 us; speedup 1.0000x reference)
//
#include <hip/hip_runtime.h>

// Problem constants
#define NB 128
#define NC 256
#define HX 31
#define WX 31
#define HC 25          // corr spatial (31-7+1)
#define WC 25
#define HO 23          // head output spatial (25-3+1)
#define WO 23
#define CHUNKS 16      // channel chunks per batch item -> 2048 blocks, 8/CU
#define CPB (NC / CHUNKS)    // 16 channels per block
#define GRP 8                // channels per group iteration (25 threads each)
#define ZCH 56               // z: 7 rows * 8 stride (16B-aligned rows)
#define WCH 48               // weights: 45 padded to 48 (12 float4)
#define CCHS 640             // corr channel stride in bf16 elems (625 padded)

#define HEAT_SZ (NB * HO * WO)       // 67712
#define REG_SZ  (NB * 4 * HO * WO)   // 270848
#define OUT_TOTAL (HEAT_SZ + REG_SZ) // 338560

// unaligned-capable float4 (x rows start at arbitrary dword offsets)
typedef float f4v __attribute__((ext_vector_type(4), aligned(4)));

__device__ __forceinline__ unsigned short f32_to_bf16_rtn(float f) {
    union { float f; unsigned int u; } v; v.f = f;
    unsigned int u = v.u;
    u += 0x7FFFu + ((u >> 16) & 1u);   // round-to-nearest-even
    return (unsigned short)(u >> 16);
}
__device__ __forceinline__ float bf16_to_f32(unsigned short h) {
    union { unsigned int u; float f; } v;
    v.u = ((unsigned int)h) << 16;
    return v.f;
}

// Writes bias into d_out (harness poisons d_out with 0xAA before every launch).
__global__ void init_out_kernel(float* __restrict__ out,
                                const float* __restrict__ heat_b,
                                const float* __restrict__ reg_b) {
    int i = blockIdx.x * 256 + threadIdx.x;
    if (i >= OUT_TOTAL) return;
    if (i < HEAT_SZ) {
        out[i] = heat_b[0];
    } else {
        int j = i - HEAT_SZ;
        int o = (j / (HO * WO)) & 3;
        out[i] = reg_b[o];
    }
}

// Exact-corr fused kernel, v4: x from global (L2/L3), corr in regs -> bf16 cs
// in LDS, conv heads gather from cs. 8 blocks/CU (VGPR<=64, LDS ~14.8KB).
__launch_bounds__(256, 8)
__global__ void fused_head_kernel(const float* __restrict__ xf,
                                  const float* __restrict__ zf,
                                  const float* __restrict__ hw,
                                  const float* __restrict__ rw,
                                  float* __restrict__ out) {
    __shared__ __align__(16) unsigned short cs[GRP * CCHS];  // 10.0 KB
    __shared__ __align__(16) float zs[GRP * ZCH];            // 1.8 KB
    __shared__ __align__(16) float ws[CPB * WCH];            // 3.0 KB

    const int tid = threadIdx.x;
    const int n = blockIdx.x >> 4;
    const int chunk = blockIdx.x & 15;
    const int cbase = chunk * CPB;

    // corr mapping: 25 threads/channel, each owns an exact 5x5 corr tile
    const int cl = tid / 25;               // channel-in-group (>=GRP -> idle)
    const int tt = tid % 25;
    const int tr = tt / 5, tc = tt % 5;
    const int i0 = tr * 5, j0 = tc * 5;

    // conv mapping: thread owns pixels tid, tid+256, (tid+512 if tid<17)
    const int p0 = tid;
    const int p1 = tid + 256;
    const int p2 = tid + 512;
    const int oy0 = p0 / 23, ox0 = p0 - oy0 * 23;
    const int oy1 = p1 / 23, ox1 = p1 - oy1 * 23;
    const int oy2 = p2 / 23, ox2 = p2 - oy2 * 23;
    const int off0 = oy0 * WC + ox0;
    const int off1 = oy1 * WC + ox1;
    const int off2 = (tid < 17) ? (oy2 * WC + ox2) : 0;

    float accH0 = 0.f, accH1 = 0.f, accH2 = 0.f;
    float accR0[4] = {0.f, 0.f, 0.f, 0.f};
    float accR1[4] = {0.f, 0.f, 0.f, 0.f};
    float accR2[4] = {0.f, 0.f, 0.f, 0.f};

    const float* xn = xf + ((size_t)n * NC + cbase) * (HX * WX);
    const float* zn = zf + ((size_t)n * NC + cbase) * 49;

    // ---- stage all 16 channels' head weights once ----
    for (int idx = tid; idx < CPB * 45; idx += 256) {
        int ch = idx / 45, j = idx - ch * 45;
        int c = cbase + ch;
        float v;
        if (j < 9) {
            v = hw[c * 9 + j];
        } else {
            int o = (j - 9) / 9;
            int jj = (j - 9) - o * 9;
            v = rw[((size_t)o * NC + c) * 9 + jj];
        }
        ws[ch * WCH + j] = v;
    }

    #pragma unroll
    for (int g0 = 0; g0 < CPB; g0 += GRP) {   // exactly 2 iterations

        // ---- stage z, rows padded to stride 8 for aligned b128 reads ----
        for (int idx = tid; idx < GRP * 49; idx += 256) {
            int ch = idx / 49, q = idx - ch * 49;
            int u = q / 7, v = q - u * 7;
            zs[ch * ZCH + u * 8 + v] = zn[(size_t)(g0 + ch) * 49 + q];
        }
        __syncthreads();

        // ---- exact corr: x rows from global, pipelined one row ahead ----
        if (cl < GRP) {
            const float* xb = xn + (size_t)(g0 + cl) * (HX * WX) + i0 * WX + j0;
            const float* zb = zs + cl * ZCH;

            float cacc[5][5];
            #pragma unroll
            for (int r = 0; r < 5; ++r)
                #pragma unroll
                for (int b = 0; b < 5; ++b) cacc[r][b] = 0.f;

            f4v c0 = *(const f4v*)(xb);
            f4v c1 = *(const f4v*)(xb + 4);
            f4v c2 = *(const f4v*)(xb + 7);   // cols j0+7..j0+10 (max col 30)

            #pragma unroll
            for (int rl = 0; rl < 11; ++rl) {
                f4v n0, n1, n2;
                if (rl < 10) {
                    const float* rp = xb + (rl + 1) * WX;
                    n0 = *(const f4v*)(rp);
                    n1 = *(const f4v*)(rp + 4);
                    n2 = *(const f4v*)(rp + 7);
                }
                const float xr[11] = {c0.x, c0.y, c0.z, c0.w,
                                      c1.x, c1.y, c1.z, c1.w,
                                      c2.y, c2.z, c2.w};
                #pragma unroll
                for (int u = 0; u < 7; ++u) {
                    const int r = rl - u;           // folds at compile time
                    if (r >= 0 && r < 5) {
                        f4v za = *(const f4v*)(zb + u * 8);      // broadcast
                        f4v zc = *(const f4v*)(zb + u * 8 + 4);
                        const float zz[7] = {za.x, za.y, za.z, za.w,
                                             zc.x, zc.y, zc.z};
                        #pragma unroll
                        for (int v = 0; v < 7; ++v)
                            #pragma unroll
                            for (int b = 0; b < 5; ++b)
                                cacc[r][b] = fmaf(zz[v], xr[b + v], cacc[r][b]);
                    }
                }
                if (rl < 10) { c0 = n0; c1 = n1; c2 = n2; }
            }
            unsigned short* cb = cs + cl * CCHS + i0 * WC + j0;
            #pragma unroll
            for (int r = 0; r < 5; ++r)
                #pragma unroll
                for (int b = 0; b < 5; ++b)
                    cb[r * WC + b] = f32_to_bf16_rtn(cacc[r][b]);
        }
        __syncthreads();

        // ---- conv heads over this group's channels ----
        for (int clc = 0; clc < GRP; ++clc) {
            float w[48];
            {
                const f4v* wp = (const f4v*)(ws + (size_t)(g0 + clc) * WCH);
                #pragma unroll
                for (int q = 0; q < 12; ++q) {     // broadcast b128
                    f4v t = wp[q];
                    w[q * 4 + 0] = t.x; w[q * 4 + 1] = t.y;
                    w[q * 4 + 2] = t.z; w[q * 4 + 3] = t.w;
                }
            }
            const unsigned short* cc = cs + clc * CCHS;

            {   // pixel p0
                const unsigned short* base = cc + off0;
                #pragma unroll
                for (int dy = 0; dy < 3; ++dy)
                    #pragma unroll
                    for (int dx = 0; dx < 3; ++dx) {
                        const float cv = bf16_to_f32(base[dy * WC + dx]);
                        const int k = dy * 3 + dx;
                        accH0    = fmaf(cv, w[k],      accH0);
                        accR0[0] = fmaf(cv, w[9 + k],  accR0[0]);
                        accR0[1] = fmaf(cv, w[18 + k], accR0[1]);
                        accR0[2] = fmaf(cv, w[27 + k], accR0[2]);
                        accR0[3] = fmaf(cv, w[36 + k], accR0[3]);
                    }
            }
            {   // pixel p1
                const unsigned short* base = cc + off1;
                #pragma unroll
                for (int dy = 0; dy < 3; ++dy)
                    #pragma unroll
                    for (int dx = 0; dx < 3; ++dx) {
                        const float cv = bf16_to_f32(base[dy * WC + dx]);
                        const int k = dy * 3 + dx;
                        accH1    = fmaf(cv, w[k],      accH1);
                        accR1[0] = fmaf(cv, w[9 + k],  accR1[0]);
                        accR1[1] = fmaf(cv, w[18 + k], accR1[1]);
                        accR1[2] = fmaf(cv, w[27 + k], accR1[2]);
                        accR1[3] = fmaf(cv, w[36 + k], accR1[3]);
                    }
            }
            if (tid < 17) {   // pixel p2
                const unsigned short* base = cc + off2;
                #pragma unroll
                for (int dy = 0; dy < 3; ++dy)
                    #pragma unroll
                    for (int dx = 0; dx < 3; ++dx) {
                        const float cv = bf16_to_f32(base[dy * WC + dx]);
                        const int k = dy * 3 + dx;
                        accH2    = fmaf(cv, w[k],      accH2);
                        accR2[0] = fmaf(cv, w[9 + k],  accR2[0]);
                        accR2[1] = fmaf(cv, w[18 + k], accR2[1]);
                        accR2[2] = fmaf(cv, w[27 + k], accR2[2]);
                        accR2[3] = fmaf(cv, w[36 + k], accR2[3]);
                    }
            }
        }
        __syncthreads();
    }

    // ---- epilogue: atomic accumulate (bias pre-written by init kernel) ----
    float* outH = out + n * (HO * WO);
    float* outR = out + HEAT_SZ + (size_t)n * 4 * (HO * WO);

    atomicAdd(&outH[p0], accH0);
    #pragma unroll
    for (int o = 0; o < 4; ++o)
        atomicAdd(&outR[o * (HO * WO) + p0], accR0[o]);

    atomicAdd(&outH[p1], accH1);
    #pragma unroll
    for (int o = 0; o < 4; ++o)
        atomicAdd(&outR[o * (HO * WO) + p1], accR1[o]);

    if (tid < 17) {
        atomicAdd(&outH[p2], accH2);
        #pragma unroll
        for (int o = 0; o < 4; ++o)
            atomicAdd(&outR[o * (HO * WO) + p2], accR2[o]);
    }
}

extern "C" void kernel_launch(void* const* d_in, const int* in_sizes, int n_in,
                              void* d_out, int out_size, void* d_ws, size_t ws_size,
                              hipStream_t stream) {
    const float* x_f    = (const float*)d_in[0];
    const float* z_f    = (const float*)d_in[1];
    const float* heat_w = (const float*)d_in[2];
    const float* heat_b = (const float*)d_in[3];
    const float* reg_w  = (const float*)d_in[4];
    const float* reg_b  = (const float*)d_in[5];
    float* out = (float*)d_out;

    init_out_kernel<<<(OUT_TOTAL + 255) / 256, 256, 0, stream>>>(out, heat_b, reg_b);
    fused_head_kernel<<<NB * CHUNKS, 256, 0, stream>>>(x_f, z_f, heat_w, reg_w, out);
}

// Round 5
// 376.133 us; speedup vs baseline: 1.9994x; 1.9994x over previous
//
#include <hip/hip_runtime.h>

// Problem constants
#define NB 128
#define NC 256
#define HX 31
#define WX 31
#define HC 25          // corr spatial (31-7+1)
#define WC 25
#define HO 23          // head output spatial (25-3+1)
#define WO 23
#define CHUNKS 8       // channel chunks per batch item -> 1024 blocks, 4/CU
#define CPB (NC / CHUNKS)    // 32 channels per block
#define GRP 10               // channels per group iteration (25 threads each)
#define ZCH 56               // z: 7 rows * 8 stride (16B-aligned rows)
#define WCH 48               // weights: 45 padded to 48 (12 float4)
#define CCH (HC * WC)        // 625

#define HEAT_SZ (NB * HO * WO)       // 67712
#define REG_SZ  (NB * 4 * HO * WO)   // 270848
#define OUT_TOTAL (HEAT_SZ + REG_SZ) // 338560

// unaligned-capable float4 (x rows start at arbitrary dword offsets)
typedef float f4v __attribute__((ext_vector_type(4), aligned(4)));

// Writes bias into d_out (harness poisons d_out with 0xAA before every launch).
__global__ void init_out_kernel(float* __restrict__ out,
                                const float* __restrict__ heat_b,
                                const float* __restrict__ reg_b) {
    int i = blockIdx.x * 256 + threadIdx.x;
    if (i >= OUT_TOTAL) return;
    if (i < HEAT_SZ) {
        out[i] = heat_b[0];
    } else {
        int j = i - HEAT_SZ;
        int o = (j / (HO * WO)) & 3;
        out[i] = reg_b[o];
    }
}

// v5 = R3 + (a) z template hoisted to registers per channel,
//          (b) conv phase loads 27 corr values up-front then 135 FMAs.
// 4 blocks/CU (VGPR target ~110 of 128, LDS ~34KB).
__launch_bounds__(256, 4)
__global__ void fused_head_kernel(const float* __restrict__ xf,
                                  const float* __restrict__ zf,
                                  const float* __restrict__ hw,
                                  const float* __restrict__ rw,
                                  float* __restrict__ out) {
    __shared__ __align__(16) float cs[GRP * CCH];   // 25.0 KB
    __shared__ __align__(16) float zs[GRP * ZCH];   // 2.2 KB
    __shared__ __align__(16) float ws[CPB * WCH];   // 6.0 KB

    const int tid = threadIdx.x;
    const int n = blockIdx.x >> 3;
    const int chunk = blockIdx.x & 7;
    const int cbase = chunk * CPB;

    // corr mapping: 25 threads/channel, each owns an exact 5x5 corr tile
    const int cl = tid / 25;               // channel-in-group (>=G -> idle)
    const int tt = tid % 25;
    const int tr = tt / 5, tc = tt % 5;
    const int i0 = tr * 5, j0 = tc * 5;

    // conv mapping: thread owns pixels tid, tid+256, (tid+512 if tid<17)
    const int p0 = tid;
    const int p1 = tid + 256;
    const int p2 = tid + 512;
    const int oy0 = p0 / 23, ox0 = p0 - oy0 * 23;
    const int oy1 = p1 / 23, ox1 = p1 - oy1 * 23;
    const int oy2 = p2 / 23, ox2 = p2 - oy2 * 23;
    const int off0 = oy0 * WC + ox0;
    const int off1 = oy1 * WC + ox1;
    const int off2 = (tid < 17) ? (oy2 * WC + ox2) : 0;

    float accH0 = 0.f, accH1 = 0.f, accH2 = 0.f;
    float accR0[4] = {0.f, 0.f, 0.f, 0.f};
    float accR1[4] = {0.f, 0.f, 0.f, 0.f};
    float accR2[4] = {0.f, 0.f, 0.f, 0.f};

    const float* xn = xf + ((size_t)n * NC + cbase) * (HX * WX);
    const float* zn = zf + ((size_t)n * NC + cbase) * 49;

    // ---- stage all 32 channels' head weights once ----
    for (int idx = tid; idx < CPB * 45; idx += 256) {
        int ch = idx / 45, j = idx - ch * 45;
        int c = cbase + ch;
        float v;
        if (j < 9) {
            v = hw[c * 9 + j];
        } else {
            int o = (j - 9) / 9;
            int jj = (j - 9) - o * 9;
            v = rw[((size_t)o * NC + c) * 9 + jj];
        }
        ws[ch * WCH + j] = v;
    }

    for (int g0 = 0; g0 < CPB; g0 += GRP) {
        const int G = (CPB - g0) < GRP ? (CPB - g0) : GRP;   // 10,10,10,2

        // ---- stage z, rows padded to stride 8 for aligned b128 reads ----
        for (int idx = tid; idx < G * 49; idx += 256) {
            int ch = idx / 49, q = idx - ch * 49;
            int u = q / 7, v = q - u * 7;
            zs[ch * ZCH + u * 8 + v] = zn[(size_t)(g0 + ch) * 49 + q];
        }
        __syncthreads();

        // ---- exact corr: z hoisted to regs, x rows from global pipelined ----
        if (cl < G) {
            const float* xb = xn + (size_t)(g0 + cl) * (HX * WX) + i0 * WX + j0;
            const float* zb = zs + cl * ZCH;

            // hoist full 7x7 template into registers (14 b128 broadcasts)
            float zr[56];
            #pragma unroll
            for (int u = 0; u < 7; ++u) {
                f4v za = *(const f4v*)(zb + u * 8);
                f4v zc = *(const f4v*)(zb + u * 8 + 4);
                zr[u * 8 + 0] = za.x; zr[u * 8 + 1] = za.y;
                zr[u * 8 + 2] = za.z; zr[u * 8 + 3] = za.w;
                zr[u * 8 + 4] = zc.x; zr[u * 8 + 5] = zc.y;
                zr[u * 8 + 6] = zc.z;
            }

            float cacc[5][5];
            #pragma unroll
            for (int r = 0; r < 5; ++r)
                #pragma unroll
                for (int b = 0; b < 5; ++b) cacc[r][b] = 0.f;

            f4v c0 = *(const f4v*)(xb);
            f4v c1 = *(const f4v*)(xb + 4);
            f4v c2 = *(const f4v*)(xb + 7);   // cols j0+7..j0+10 (max col 30)

            #pragma unroll
            for (int rl = 0; rl < 11; ++rl) {
                f4v n0, n1, n2;
                if (rl < 10) {
                    const float* rp = xb + (rl + 1) * WX;
                    n0 = *(const f4v*)(rp);
                    n1 = *(const f4v*)(rp + 4);
                    n2 = *(const f4v*)(rp + 7);
                }
                const float xr[11] = {c0.x, c0.y, c0.z, c0.w,
                                      c1.x, c1.y, c1.z, c1.w,
                                      c2.y, c2.z, c2.w};
                #pragma unroll
                for (int u = 0; u < 7; ++u) {
                    const int r = rl - u;           // folds at compile time
                    if (r >= 0 && r < 5) {
                        #pragma unroll
                        for (int v = 0; v < 7; ++v)
                            #pragma unroll
                            for (int b = 0; b < 5; ++b)
                                cacc[r][b] = fmaf(zr[u * 8 + v], xr[b + v],
                                                  cacc[r][b]);
                    }
                }
                if (rl < 10) { c0 = n0; c1 = n1; c2 = n2; }
            }
            float* cb = cs + cl * CCH + i0 * WC + j0;
            #pragma unroll
            for (int r = 0; r < 5; ++r)
                #pragma unroll
                for (int b = 0; b < 5; ++b) cb[r * WC + b] = cacc[r][b];
        }
        __syncthreads();

        // ---- conv heads: per channel, load 27 corr vals then 135 FMAs ----
        for (int clc = 0; clc < G; ++clc) {
            float w[48];
            {
                const f4v* wp = (const f4v*)(ws + (size_t)(g0 + clc) * WCH);
                #pragma unroll
                for (int q = 0; q < 12; ++q) {     // broadcast b128
                    f4v t = wp[q];
                    w[q * 4 + 0] = t.x; w[q * 4 + 1] = t.y;
                    w[q * 4 + 2] = t.z; w[q * 4 + 3] = t.w;
                }
            }
            const float* cc = cs + clc * CCH;

            // phase 1: gather all corr inputs (independent LDS reads)
            float cv0[9], cv1[9], cv2[9];
            {
                const float* b0 = cc + off0;
                const float* b1 = cc + off1;
                #pragma unroll
                for (int dy = 0; dy < 3; ++dy)
                    #pragma unroll
                    for (int dx = 0; dx < 3; ++dx) {
                        cv0[dy * 3 + dx] = b0[dy * WC + dx];
                        cv1[dy * 3 + dx] = b1[dy * WC + dx];
                    }
            }
            if (tid < 17) {
                const float* b2 = cc + off2;
                #pragma unroll
                for (int dy = 0; dy < 3; ++dy)
                    #pragma unroll
                    for (int dx = 0; dx < 3; ++dx)
                        cv2[dy * 3 + dx] = b2[dy * WC + dx];
            }

            // phase 2: straight FMA streams
            #pragma unroll
            for (int k = 0; k < 9; ++k) {
                const float a = cv0[k], b = cv1[k];
                accH0    = fmaf(a, w[k],      accH0);
                accH1    = fmaf(b, w[k],      accH1);
                accR0[0] = fmaf(a, w[9 + k],  accR0[0]);
                accR1[0] = fmaf(b, w[9 + k],  accR1[0]);
                accR0[1] = fmaf(a, w[18 + k], accR0[1]);
                accR1[1] = fmaf(b, w[18 + k], accR1[1]);
                accR0[2] = fmaf(a, w[27 + k], accR0[2]);
                accR1[2] = fmaf(b, w[27 + k], accR1[2]);
                accR0[3] = fmaf(a, w[36 + k], accR0[3]);
                accR1[3] = fmaf(b, w[36 + k], accR1[3]);
            }
            if (tid < 17) {
                #pragma unroll
                for (int k = 0; k < 9; ++k) {
                    const float a = cv2[k];
                    accH2    = fmaf(a, w[k],      accH2);
                    accR2[0] = fmaf(a, w[9 + k],  accR2[0]);
                    accR2[1] = fmaf(a, w[18 + k], accR2[1]);
                    accR2[2] = fmaf(a, w[27 + k], accR2[2]);
                    accR2[3] = fmaf(a, w[36 + k], accR2[3]);
                }
            }
        }
        __syncthreads();
    }

    // ---- epilogue: atomic accumulate (bias pre-written by init kernel) ----
    float* outH = out + n * (HO * WO);
    float* outR = out + HEAT_SZ + (size_t)n * 4 * (HO * WO);

    atomicAdd(&outH[p0], accH0);
    #pragma unroll
    for (int o = 0; o < 4; ++o)
        atomicAdd(&outR[o * (HO * WO) + p0], accR0[o]);

    atomicAdd(&outH[p1], accH1);
    #pragma unroll
    for (int o = 0; o < 4; ++o)
        atomicAdd(&outR[o * (HO * WO) + p1], accR1[o]);

    if (tid < 17) {
        atomicAdd(&outH[p2], accH2);
        #pragma unroll
        for (int o = 0; o < 4; ++o)
            atomicAdd(&outR[o * (HO * WO) + p2], accR2[o]);
    }
}

extern "C" void kernel_launch(void* const* d_in, const int* in_sizes, int n_in,
                              void* d_out, int out_size, void* d_ws, size_t ws_size,
                              hipStream_t stream) {
    const float* x_f    = (const float*)d_in[0];
    const float* z_f    = (const float*)d_in[1];
    const float* heat_w = (const float*)d_in[2];
    const float* heat_b = (const float*)d_in[3];
    const float* reg_w  = (const float*)d_in[4];
    const float* reg_b  = (const float*)d_in[5];
    float* out = (float*)d_out;

    init_out_kernel<<<(OUT_TOTAL + 255) / 256, 256, 0, stream>>>(out, heat_b, reg_b);
    fused_head_kernel<<<NB * CHUNKS, 256, 0, stream>>>(x_f, z_f, heat_w, reg_w, out);
}

// Round 6
// 276.050 us; speedup vs baseline: 2.7243x; 1.3626x over previous
//
#include <hip/hip_runtime.h>

// Problem constants
#define NB 128
#define NC 256
#define HX 31
#define WX 31
#define HC 25          // corr spatial (31-7+1)
#define WC 25
#define HO 23          // head output spatial (25-3+1)
#define WO 23
#define CHUNKS 8       // channel chunks per batch item -> 1024 blocks, 4/CU
#define CPB (NC / CHUNKS)    // 32 channels per block
#define GRP 8                // channels per group iteration (4 clean groups)
#define ZCH 56               // z: 7 rows * 8 stride (16B-aligned rows)
#define CCH (HC * WC)        // 625

#define HEAT_SZ (NB * HO * WO)       // 67712
#define REG_SZ  (NB * 4 * HO * WO)   // 270848
#define OUT_TOTAL (HEAT_SZ + REG_SZ) // 338560

// unaligned-capable float4 (x rows start at arbitrary dword offsets)
typedef float f4v __attribute__((ext_vector_type(4), aligned(4)));

// Writes bias into d_out (harness poisons d_out with 0xAA before every launch).
__global__ void init_out_kernel(float* __restrict__ out,
                                const float* __restrict__ heat_b,
                                const float* __restrict__ reg_b) {
    int i = blockIdx.x * 256 + threadIdx.x;
    if (i >= OUT_TOTAL) return;
    if (i < HEAT_SZ) {
        out[i] = heat_b[0];
    } else {
        int j = i - HEAT_SZ;
        int o = (j / (HO * WO)) & 3;
        out[i] = reg_b[o];
    }
}

// v6 = R5 code shape with the correct register budget:
//  - __launch_bounds__(256,2): empirically VGPR budget = 256/arg2 = 128.
//    Live set ~110 regs (zr 49 + cacc 25 + x-pipe 24 + addr) -> no spill.
//  - weights read directly from global with block-uniform addresses
//    (scalar/SMEM path) -> w[48] b128 broadcasts leave the LDS pipe.
//  - GRP=8, CPB=32: 4 clean groups, channel loop fully unrolled.
__launch_bounds__(256, 2)
__global__ void fused_head_kernel(const float* __restrict__ xf,
                                  const float* __restrict__ zf,
                                  const float* __restrict__ hw,
                                  const float* __restrict__ rw,
                                  float* __restrict__ out) {
    __shared__ __align__(16) float cs[GRP * CCH];   // 20.0 KB
    __shared__ __align__(16) float zs[GRP * ZCH];   // 1.8 KB

    const int tid = threadIdx.x;
    const int n = blockIdx.x >> 3;
    const int chunk = blockIdx.x & 7;
    const int cbase = chunk * CPB;

    // corr mapping: 25 threads/channel, 8 channels -> tids 0..199 active
    const int cl = tid / 25;               // channel-in-group (>=GRP -> idle)
    const int tt = tid % 25;
    const int tr = tt / 5, tc = tt % 5;
    const int i0 = tr * 5, j0 = tc * 5;

    // conv mapping: thread owns pixels tid, tid+256, (tid+512 if tid<17)
    const int p0 = tid;
    const int p1 = tid + 256;
    const int p2 = tid + 512;
    const int oy0 = p0 / 23, ox0 = p0 - oy0 * 23;
    const int oy1 = p1 / 23, ox1 = p1 - oy1 * 23;
    const int oy2 = p2 / 23, ox2 = p2 - oy2 * 23;
    const int off0 = oy0 * WC + ox0;
    const int off1 = oy1 * WC + ox1;
    const int off2 = (tid < 17) ? (oy2 * WC + ox2) : 0;

    float accH0 = 0.f, accH1 = 0.f, accH2 = 0.f;
    float accR0[4] = {0.f, 0.f, 0.f, 0.f};
    float accR1[4] = {0.f, 0.f, 0.f, 0.f};
    float accR2[4] = {0.f, 0.f, 0.f, 0.f};

    const float* xn = xf + ((size_t)n * NC + cbase) * (HX * WX);
    const float* zn = zf + ((size_t)n * NC + cbase) * 49;

    for (int g0 = 0; g0 < CPB; g0 += GRP) {   // 4 clean groups of 8

        // ---- stage z, rows padded to stride 8 for aligned b128 reads ----
        for (int idx = tid; idx < GRP * 49; idx += 256) {
            int ch = idx / 49, q = idx - ch * 49;
            int u = q / 7, v = q - u * 7;
            zs[ch * ZCH + u * 8 + v] = zn[(size_t)(g0 + ch) * 49 + q];
        }
        __syncthreads();

        // ---- exact corr: z hoisted to regs, x rows from global pipelined ----
        if (cl < GRP) {
            const float* xb = xn + (size_t)(g0 + cl) * (HX * WX) + i0 * WX + j0;
            const float* zb = zs + cl * ZCH;

            // hoist full 7x7 template into registers (14 b128 broadcasts)
            float zr[56];
            #pragma unroll
            for (int u = 0; u < 7; ++u) {
                f4v za = *(const f4v*)(zb + u * 8);
                f4v zc = *(const f4v*)(zb + u * 8 + 4);
                zr[u * 8 + 0] = za.x; zr[u * 8 + 1] = za.y;
                zr[u * 8 + 2] = za.z; zr[u * 8 + 3] = za.w;
                zr[u * 8 + 4] = zc.x; zr[u * 8 + 5] = zc.y;
                zr[u * 8 + 6] = zc.z;
            }

            float cacc[5][5];
            #pragma unroll
            for (int r = 0; r < 5; ++r)
                #pragma unroll
                for (int b = 0; b < 5; ++b) cacc[r][b] = 0.f;

            f4v c0 = *(const f4v*)(xb);
            f4v c1 = *(const f4v*)(xb + 4);
            f4v c2 = *(const f4v*)(xb + 7);   // cols j0+7..j0+10 (max col 30)

            #pragma unroll
            for (int rl = 0; rl < 11; ++rl) {
                f4v n0, n1, n2;
                if (rl < 10) {
                    const float* rp = xb + (rl + 1) * WX;
                    n0 = *(const f4v*)(rp);
                    n1 = *(const f4v*)(rp + 4);
                    n2 = *(const f4v*)(rp + 7);
                }
                const float xr[11] = {c0.x, c0.y, c0.z, c0.w,
                                      c1.x, c1.y, c1.z, c1.w,
                                      c2.y, c2.z, c2.w};
                #pragma unroll
                for (int u = 0; u < 7; ++u) {
                    const int r = rl - u;           // folds at compile time
                    if (r >= 0 && r < 5) {
                        #pragma unroll
                        for (int v = 0; v < 7; ++v)
                            #pragma unroll
                            for (int b = 0; b < 5; ++b)
                                cacc[r][b] = fmaf(zr[u * 8 + v], xr[b + v],
                                                  cacc[r][b]);
                    }
                }
                if (rl < 10) { c0 = n0; c1 = n1; c2 = n2; }
            }
            float* cb = cs + cl * CCH + i0 * WC + j0;
            #pragma unroll
            for (int r = 0; r < 5; ++r)
                #pragma unroll
                for (int b = 0; b < 5; ++b) cb[r * WC + b] = cacc[r][b];
        }
        __syncthreads();

        // ---- conv heads: weights from global (block-uniform -> s_load) ----
        #pragma unroll
        for (int clc = 0; clc < GRP; ++clc) {
            const int c = cbase + g0 + clc;
            // uniform scalar loads (SMEM pipe, L2-hot) — not LDS
            float w[45];
            {
                const float* whp = hw + c * 9;
                #pragma unroll
                for (int k = 0; k < 9; ++k) w[k] = whp[k];
                #pragma unroll
                for (int o = 0; o < 4; ++o) {
                    const float* wrp = rw + ((size_t)o * NC + c) * 9;
                    #pragma unroll
                    for (int k = 0; k < 9; ++k) w[9 + o * 9 + k] = wrp[k];
                }
            }
            const float* cc = cs + clc * CCH;

            // phase 1: gather corr inputs (independent LDS reads)
            float cv0[9], cv1[9], cv2[9];
            {
                const float* b0 = cc + off0;
                const float* b1 = cc + off1;
                #pragma unroll
                for (int dy = 0; dy < 3; ++dy)
                    #pragma unroll
                    for (int dx = 0; dx < 3; ++dx) {
                        cv0[dy * 3 + dx] = b0[dy * WC + dx];
                        cv1[dy * 3 + dx] = b1[dy * WC + dx];
                    }
            }
            if (tid < 17) {
                const float* b2 = cc + off2;
                #pragma unroll
                for (int dy = 0; dy < 3; ++dy)
                    #pragma unroll
                    for (int dx = 0; dx < 3; ++dx)
                        cv2[dy * 3 + dx] = b2[dy * WC + dx];
            }

            // phase 2: straight FMA streams
            #pragma unroll
            for (int k = 0; k < 9; ++k) {
                const float a = cv0[k], b = cv1[k];
                accH0    = fmaf(a, w[k],      accH0);
                accH1    = fmaf(b, w[k],      accH1);
                accR0[0] = fmaf(a, w[9 + k],  accR0[0]);
                accR1[0] = fmaf(b, w[9 + k],  accR1[0]);
                accR0[1] = fmaf(a, w[18 + k], accR0[1]);
                accR1[1] = fmaf(b, w[18 + k], accR1[1]);
                accR0[2] = fmaf(a, w[27 + k], accR0[2]);
                accR1[2] = fmaf(b, w[27 + k], accR1[2]);
                accR0[3] = fmaf(a, w[36 + k], accR0[3]);
                accR1[3] = fmaf(b, w[36 + k], accR1[3]);
            }
            if (tid < 17) {
                #pragma unroll
                for (int k = 0; k < 9; ++k) {
                    const float a = cv2[k];
                    accH2    = fmaf(a, w[k],      accH2);
                    accR2[0] = fmaf(a, w[9 + k],  accR2[0]);
                    accR2[1] = fmaf(a, w[18 + k], accR2[1]);
                    accR2[2] = fmaf(a, w[27 + k], accR2[2]);
                    accR2[3] = fmaf(a, w[36 + k], accR2[3]);
                }
            }
        }
        __syncthreads();
    }

    // ---- epilogue: atomic accumulate (bias pre-written by init kernel) ----
    float* outH = out + n * (HO * WO);
    float* outR = out + HEAT_SZ + (size_t)n * 4 * (HO * WO);

    atomicAdd(&outH[p0], accH0);
    #pragma unroll
    for (int o = 0; o < 4; ++o)
        atomicAdd(&outR[o * (HO * WO) + p0], accR0[o]);

    atomicAdd(&outH[p1], accH1);
    #pragma unroll
    for (int o = 0; o < 4; ++o)
        atomicAdd(&outR[o * (HO * WO) + p1], accR1[o]);

    if (tid < 17) {
        atomicAdd(&outH[p2], accH2);
        #pragma unroll
        for (int o = 0; o < 4; ++o)
            atomicAdd(&outR[o * (HO * WO) + p2], accR2[o]);
    }
}

extern "C" void kernel_launch(void* const* d_in, const int* in_sizes, int n_in,
                              void* d_out, int out_size, void* d_ws, size_t ws_size,
                              hipStream_t stream) {
    const float* x_f    = (const float*)d_in[0];
    const float* z_f    = (const float*)d_in[1];
    const float* heat_w = (const float*)d_in[2];
    const float* heat_b = (const float*)d_in[3];
    const float* reg_w  = (const float*)d_in[4];
    const float* reg_b  = (const float*)d_in[5];
    float* out = (float*)d_out;

    init_out_kernel<<<(OUT_TOTAL + 255) / 256, 256, 0, stream>>>(out, heat_b, reg_b);
    fused_head_kernel<<<NB * CHUNKS, 256, 0, stream>>>(x_f, z_f, heat_w, reg_w, out);
}